// Round 3
// baseline (5586.122 us; speedup 1.0000x reference)
//
#include <hip/hip_runtime.h>
#include <cstdint>
#include <cstddef>

// GRUCore B=256 T=128 D=1024 H=1024 — Round 3: persistent cooperative recurrence.
// prep -> gi GEMM (unchanged) -> ONE cooperative kernel for all 128 steps
// (W_hh LDS-resident + T2 swizzle + counted-vmcnt h pipeline + grid barrier)
// -> fused LayerNorm + residual.

constexpr int kB = 256, kT = 128, kD = 1024, kH = 1024, kG = 3072;

typedef unsigned short u16;
typedef unsigned int u32;
typedef __attribute__((ext_vector_type(4))) float f32x4;
typedef __attribute__((ext_vector_type(8))) short s16x8;
typedef __attribute__((ext_vector_type(8))) u16 u16x8;
typedef __attribute__((ext_vector_type(4))) u16 u16x4;

__device__ __forceinline__ u16 f2bf(float f) {
  u32 u = __builtin_bit_cast(u32, f);
  u += 0x7fffu + ((u >> 16) & 1u);
  return (u16)(u >> 16);
}
__device__ __forceinline__ float bf2f(u16 s) {
  return __builtin_bit_cast(float, (u32)s << 16);
}
__device__ __forceinline__ void glds16(const void* g, void* l) {
  __builtin_amdgcn_global_load_lds(
      (const __attribute__((address_space(1))) u32*)g,
      (__attribute__((address_space(3))) u32*)l, 16, 0, 0);
}
__device__ __forceinline__ float sigm(float x) { return 1.f / (1.f + __expf(-x)); }
__device__ __forceinline__ float ftanh(float x) {
  float e = __expf(2.f * x);
  return 1.f - 2.f / (e + 1.f);
}

// ---------------- prep kernels ----------------

__global__ __launch_bounds__(256) void cvt_bf16_k(const float* __restrict__ src, u16* __restrict__ dst) {
  size_t i = ((size_t)blockIdx.x * 256 + threadIdx.x) * 8;
  float4 a = *(const float4*)(src + i);
  float4 b2 = *(const float4*)(src + i + 4);
  u16x8 o;
  o[0] = f2bf(a.x); o[1] = f2bf(a.y); o[2] = f2bf(a.z); o[3] = f2bf(a.w);
  o[4] = f2bf(b2.x); o[5] = f2bf(b2.y); o[6] = f2bf(b2.z); o[7] = f2bf(b2.w);
  *(u16x8*)(dst + i) = o;
}

// gate-interleave permutation: out row n' = j*48+s (s: 0-15 r, 16-31 z, 32-47 n)
//   <- orig row (s>>4)*1024 + j*16 + (s&15)
__global__ __launch_bounds__(256) void perm_w_k(const float* __restrict__ Wih, const float* __restrict__ Whh,
                                                const float* __restrict__ bih, const float* __restrict__ bhh,
                                                u16* __restrict__ Wihp, u16* __restrict__ Whhp,
                                                float* __restrict__ bihp, float* __restrict__ bhhp) {
  int np = blockIdx.x, tid = threadIdx.x;
  int j = np / 48, s2 = np - j * 48;
  int orig = (s2 >> 4) * kH + j * 16 + (s2 & 15);
  float4 a = ((const float4*)(Wih + (size_t)orig * kD))[tid];
  float4 b2 = ((const float4*)(Whh + (size_t)orig * kH))[tid];
  u16x4 oa, ob;
  oa[0] = f2bf(a.x); oa[1] = f2bf(a.y); oa[2] = f2bf(a.z); oa[3] = f2bf(a.w);
  ob[0] = f2bf(b2.x); ob[1] = f2bf(b2.y); ob[2] = f2bf(b2.z); ob[3] = f2bf(b2.w);
  *(u16x4*)(Wihp + (size_t)np * kD + tid * 4) = oa;
  *(u16x4*)(Whhp + (size_t)np * kH + tid * 4) = ob;
  if (tid == 0) { bihp[np] = bih[orig]; bhhp[np] = bhh[orig]; }
}

// ---------------- gi GEMM: m97-style 128x128 bf16 MFMA (unchanged) ----------------

__global__ __launch_bounds__(256) void gi_gemm_k(const u16* __restrict__ A, const u16* __restrict__ Bw,
                                                 const float* __restrict__ bih, u16* __restrict__ gi) {
  __shared__ u16 As[128 * 32];
  __shared__ u16 Bs[128 * 32];
  int bid = blockIdx.x;
  int b2 = (bid & 7) * 768 + (bid >> 3);  // XCD swizzle (6144 % 8 == 0, bijective)
  int m0 = (b2 / 24) * 128, n0 = (b2 % 24) * 128;
  int tid = threadIdx.x, w = tid >> 6, lane = tid & 63;
  int wm = (w >> 1) * 64, wn = (w & 1) * 64;
  f32x4 acc[4][4] = {};
  for (int kt = 0; kt < 32; ++kt) {
    int k0 = kt * 32;
#pragma unroll
    for (int p = 0; p < 2; ++p) {
      int c = w * 2 + p;
      int e = c * 512 + lane * 8;
      int row = e >> 5, kk = e & 31;
      glds16(A + (size_t)(m0 + row) * kD + k0 + kk, (char*)As + c * 1024);
      glds16(Bw + (size_t)(n0 + row) * kD + k0 + kk, (char*)Bs + c * 1024);
    }
    __syncthreads();
    int fr = lane & 15, fo = (lane >> 4) * 16;
    s16x8 af[4], bfr[4];
#pragma unroll
    for (int mi = 0; mi < 4; ++mi)
      af[mi] = *(const s16x8*)((const char*)As + (wm + mi * 16 + fr) * 64 + fo);
#pragma unroll
    for (int ni = 0; ni < 4; ++ni)
      bfr[ni] = *(const s16x8*)((const char*)Bs + (wn + ni * 16 + fr) * 64 + fo);
#pragma unroll
    for (int mi = 0; mi < 4; ++mi)
#pragma unroll
      for (int ni = 0; ni < 4; ++ni)
        acc[mi][ni] = __builtin_amdgcn_mfma_f32_16x16x32_bf16(af[mi], bfr[ni], acc[mi][ni], 0, 0, 0);
    __syncthreads();
  }
  int fr = lane & 15, rb = (lane >> 4) * 4;
#pragma unroll
  for (int ni = 0; ni < 4; ++ni) {
    int n = n0 + wn + ni * 16 + fr;
    float bv = bih[n];
#pragma unroll
    for (int mi = 0; mi < 4; ++mi) {
#pragma unroll
      for (int i2 = 0; i2 < 4; ++i2) {
        int m = m0 + wm + mi * 16 + rb + i2;
        int b = m >> 7, t = m & 127;
        gi[((size_t)t * kB + b) * kG + n] = f2bf(acc[mi][ni][i2] + bv);
      }
    }
  }
}

// ---------------- persistent recurrence kernel ----------------
// 256 blocks (cooperative, 1/CU), 256 threads. Block (Ng=bid&63, Mg=bid>>6):
// h-cols Ng*16..+16, batches Mg*64..+64. W stripe [48][1024] bf16 LDS-resident
// (XOR-swizzled). Per step: 8 h-chunks [64][128] staged via glds16 (3-buffer,
// vmcnt(4) 2-deep pipeline), 96 MFMA/wave, epilogue, grid barrier.

__device__ __forceinline__ void grid_bar(u32* cnt, u32 phase) {
  __syncthreads();
  if (threadIdx.x == 0) {
    __threadfence();  // release: flush this XCD's L2
    __hip_atomic_fetch_add(cnt, 1u, __ATOMIC_RELEASE, __HIP_MEMORY_SCOPE_AGENT);
    u32 tgt = phase * 256u;
    while (__hip_atomic_load(cnt, __ATOMIC_ACQUIRE, __HIP_MEMORY_SCOPE_AGENT) < tgt)
      __builtin_amdgcn_s_sleep(2);
    __threadfence();  // acquire: invalidate L1/L2 stale lines
  }
  __syncthreads();
}

__global__ void gru_seq_k(const u16* __restrict__ Whh, const u16* __restrict__ gi,
                          const float* __restrict__ bhh, const int* __restrict__ is_init,
                          const float* __restrict__ hx,
                          u16* __restrict__ hb0, u16* __restrict__ hb1,
                          float* __restrict__ Hs, u32* __restrict__ cnt) {
  extern __shared__ char smem[];
  char* Wc = smem;              // 48*1024 bf16 = 98304 B, swizzled
  char* Hc = smem + 98304;      // 3 x (64*128 bf16 = 16384 B), swizzled
  int bid = blockIdx.x;
  int Ng = bid & 63, Mg = bid >> 6;
  int tid = threadIdx.x, w = tid >> 6, lane = tid & 63;
  int fr = lane & 15, q = lane >> 4;
  int fo = q * 16;              // byte offset of k-fragment within 64B slice
  int sw = (fr & 7) << 4;       // T2 XOR swizzle (rows differ by fr)
  int hcol = Ng * 16 + fr;

  // ---- prologue: init hb0 + hp regs; load W into LDS (inverse-swizzled src) ----
  float hp[4];
#pragma unroll
  for (int i = 0; i < 4; ++i) {
    int b = Mg * 64 + w * 16 + q * 4 + i;
    float v = hx[(size_t)b * kH + hcol];
    hp[i] = v;
    hb0[(size_t)b * kH + hcol] = f2bf(v);
  }
  const u16* Wbase = Whh + (size_t)(48 * Ng) * kH;
#pragma unroll 4
  for (int i = 0; i < 24; ++i) {
    int c = w * 24 + i;
    int d = c * 512 + lane * 8;                       // u16 units, < 49152
    int row = d >> 10;                                // 2048B rows
    int col = (d & 1023) ^ ((row & 7) << 3);          // involution, 16B-aligned
    glds16(Wbase + (size_t)row * kH + col, Wc + c * 1024);
  }
  asm volatile("s_waitcnt vmcnt(0)" ::: "memory");
  grid_bar(cnt, 1);

  float br = bhh[48 * Ng + fr], bz = bhh[48 * Ng + 16 + fr], bn = bhh[48 * Ng + 32 + fr];

  for (int t = 0; t < kT; ++t) {
    const u16* hbp = (t & 1) ? hb1 : hb0;
    u16* hbn = (t & 1) ? hb0 : hb1;
    const u16* Hbase = hbp + (size_t)(Mg * 64) * kH;

    auto stage = [&](int kc) {
#pragma unroll
      for (int i = 0; i < 4; ++i) {
        int c = w * 4 + i;
        int d = c * 512 + lane * 8;                   // u16 units, < 8192
        int row = d >> 7;                             // 256B rows
        int col = (d & 127) ^ ((row & 7) << 3);
        glds16(Hbase + (size_t)row * kH + kc * 128 + col,
               Hc + (kc % 3) * 16384 + c * 1024);
      }
    };

    f32x4 acc[3] = {};
    stage(0); stage(1);
    asm volatile("s_waitcnt vmcnt(4)" ::: "memory");  // chunk 0 landed
    __builtin_amdgcn_s_barrier();
#pragma unroll
    for (int kc = 0; kc < 8; ++kc) {
      if (kc + 2 < 8) stage(kc + 2);
      const char* hbuf = Hc + (kc % 3) * 16384;
      int hrow = w * 16 + fr;
#pragma unroll
      for (int ks = 0; ks < 4; ++ks) {
        s16x8 hf8 = *(const s16x8*)(hbuf + ((hrow * 256 + ks * 64 + fo) ^ sw));
#pragma unroll
        for (int g = 0; g < 3; ++g) {
          int wrow = g * 16 + fr;
          const s16x8* wp = (const s16x8*)(Wc + ((wrow * 2048 + kc * 256 + ks * 64 + fo) ^ sw));
          acc[g] = __builtin_amdgcn_mfma_f32_16x16x32_bf16(hf8, *wp, acc[g], 0, 0, 0);
        }
      }
      if (kc < 7) {
        if (kc <= 5) asm volatile("s_waitcnt vmcnt(4)" ::: "memory");
        else         asm volatile("s_waitcnt vmcnt(0)" ::: "memory");
        __builtin_amdgcn_s_barrier();
      }
    }
    // ---- epilogue: gates + h update (h_prev kept in registers) ----
#pragma unroll
    for (int i = 0; i < 4; ++i) {
      int b = Mg * 64 + w * 16 + q * 4 + i;
      float m = is_init[b * kT + t] ? 0.f : 1.f;
      size_t gb = ((size_t)t * kB + b) * (size_t)kG + 48 * Ng;
      float gir = bf2f(gi[gb + fr]);
      float giz = bf2f(gi[gb + 16 + fr]);
      float gin = bf2f(gi[gb + 32 + fr]);
      float r = sigm(gir + m * acc[0][i] + br);
      float z = sigm(giz + m * acc[1][i] + bz);
      float n = ftanh(gin + r * (m * acc[2][i] + bn));
      float hv = (1.f - z) * n + z * (m * hp[i]);
      hp[i] = hv;
      hbn[(size_t)b * kH + hcol] = f2bf(hv);
      Hs[((size_t)b * kT + t) * kH + hcol] = hv;
    }
    grid_bar(cnt, (u32)(t + 2));
  }
}

// ---------------- LayerNorm + gated residual ----------------

__global__ __launch_bounds__(256) void ln_res_k(const float* __restrict__ Hs, const float* __restrict__ x,
                                                const float* __restrict__ g, const float* __restrict__ be,
                                                const float* __restrict__ rg, float* __restrict__ Y) {
  int row = blockIdx.x;
  int tid = threadIdx.x;
  size_t base = (size_t)row * kH;
  float4 v = ((const float4*)(Hs + base))[tid];
  float s = v.x + v.y + v.z + v.w;
  float ss = v.x * v.x + v.y * v.y + v.z * v.z + v.w * v.w;
#pragma unroll
  for (int off = 32; off > 0; off >>= 1) {
    s += __shfl_down(s, off);
    ss += __shfl_down(ss, off);
  }
  __shared__ float red[8];
  int w = tid >> 6;
  if ((tid & 63) == 0) { red[w] = s; red[4 + w] = ss; }
  __syncthreads();
  s = red[0] + red[1] + red[2] + red[3];
  ss = red[4] + red[5] + red[6] + red[7];
  float mu = s * (1.f / kH);
  float rs = rsqrtf(ss * (1.f / kH) - mu * mu + 1e-5f);
  float4 xv = ((const float4*)(x + base))[tid];
  float4 gv = ((const float4*)g)[tid];
  float4 bv = ((const float4*)be)[tid];
  float4 rv = ((const float4*)rg)[tid];
  float4 o;
  o.x = (v.x - mu) * rs * gv.x + bv.x + xv.x * sigm(rv.x);
  o.y = (v.y - mu) * rs * gv.y + bv.y + xv.y * sigm(rv.y);
  o.z = (v.z - mu) * rs * gv.z + bv.z + xv.z * sigm(rv.z);
  o.w = (v.w - mu) * rs * gv.w + bv.w + xv.w * sigm(rv.w);
  ((float4*)(Y + base))[tid] = o;
}

// ---------------- launch ----------------

extern "C" void kernel_launch(void* const* d_in, const int* in_sizes, int n_in,
                              void* d_out, int out_size, void* d_ws, size_t ws_size,
                              hipStream_t stream) {
  const float* x = (const float*)d_in[0];
  const float* hx = (const float*)d_in[1];
  const int* is_init = (const int*)d_in[2];
  const float* Wih = (const float*)d_in[3];
  const float* Whh = (const float*)d_in[4];
  const float* bih = (const float*)d_in[5];
  const float* bhh = (const float*)d_in[6];
  const float* lng = (const float*)d_in[7];
  const float* lnb = (const float*)d_in[8];
  const float* rg = (const float*)d_in[9];
  float* Y = (float*)d_out;
  float* Hs = Y + (size_t)kB * kT * kH;

  char* ws = (char*)d_ws;
  u16* xb = (u16*)(ws + 0);                //  67,108,864 B
  u16* Wihp = (u16*)(ws + 67108864);       //   6,291,456
  u16* Whhp = (u16*)(ws + 73400320);       //   6,291,456
  float* bihp = (float*)(ws + 79691776);   //      12,288
  float* bhhp = (float*)(ws + 79704064);   //      12,288
  u32* cnt = (u32*)(ws + 79716352);        //         128
  u16* hb0 = (u16*)(ws + 79716480);        //     524,288
  u16* hb1 = (u16*)(ws + 80240768);        //     524,288
  u16* gi = (u16*)(ws + 80765056);         // 201,326,592 -> total 282,091,648
  if (ws_size < 282091648ull) return;      // fail loudly rather than corrupt

  cvt_bf16_k<<<16384, 256, 0, stream>>>(x, xb);
  perm_w_k<<<3072, 256, 0, stream>>>(Wih, Whh, bih, bhh, Wihp, Whhp, bihp, bhhp);
  gi_gemm_k<<<6144, 256, 0, stream>>>(xb, Wihp, bihp, gi);
  hipMemsetAsync(cnt, 0, 128, stream);

  (void)hipFuncSetAttribute((const void*)gru_seq_k,
                            hipFuncAttributeMaxDynamicSharedMemorySize, 147456);
  void* args[] = {(void*)&Whhp, (void*)&gi, (void*)&bhhp, (void*)&is_init,
                  (void*)&hx, (void*)&hb0, (void*)&hb1, (void*)&Hs, (void*)&cnt};
  hipLaunchCooperativeKernel((void*)gru_seq_k, dim3(256), dim3(256), args, 147456, stream);

  ln_res_k<<<32768, 256, 0, stream>>>(Hs, x, lng, lnb, rg, Y);
}

// Round 5
// 1809.518 us; speedup vs baseline: 3.0871x; 3.0871x over previous
//
#include <hip/hip_runtime.h>
#include <cstdint>
#include <cstddef>

// GRUCore B=256 T=128 D=1024 H=1024 — Round 5: resubmit of round-4 kernel
// (round 4 hit GPUAcquisitionTimeout; no kernel verdict).
// Per-step launches with swizzled LDS + chunk-major W streaming +
// counted-vmcnt 2-deep pipeline.

constexpr int kB = 256, kT = 128, kD = 1024, kH = 1024, kG = 3072;

typedef unsigned short u16;
typedef unsigned int u32;
typedef __attribute__((ext_vector_type(4))) float f32x4;
typedef __attribute__((ext_vector_type(8))) short s16x8;
typedef __attribute__((ext_vector_type(8))) u16 u16x8;
typedef __attribute__((ext_vector_type(4))) u16 u16x4;

__device__ __forceinline__ u16 f2bf(float f) {
  u32 u = __builtin_bit_cast(u32, f);
  u += 0x7fffu + ((u >> 16) & 1u);
  return (u16)(u >> 16);
}
__device__ __forceinline__ float bf2f(u16 s) {
  return __builtin_bit_cast(float, (u32)s << 16);
}
__device__ __forceinline__ void glds16(const void* g, void* l) {
  __builtin_amdgcn_global_load_lds(
      (const __attribute__((address_space(1))) u32*)g,
      (__attribute__((address_space(3))) u32*)l, 16, 0, 0);
}
__device__ __forceinline__ float sigm(float x) { return 1.f / (1.f + __expf(-x)); }
__device__ __forceinline__ float ftanh(float x) {
  float e = __expf(2.f * x);
  return 1.f - 2.f / (e + 1.f);
}

// ---------------- prep kernels ----------------

__global__ __launch_bounds__(256) void cvt_bf16_k(const float* __restrict__ src, u16* __restrict__ dst) {
  size_t i = ((size_t)blockIdx.x * 256 + threadIdx.x) * 8;
  float4 a = *(const float4*)(src + i);
  float4 b2 = *(const float4*)(src + i + 4);
  u16x8 o;
  o[0] = f2bf(a.x); o[1] = f2bf(a.y); o[2] = f2bf(a.z); o[3] = f2bf(a.w);
  o[4] = f2bf(b2.x); o[5] = f2bf(b2.y); o[6] = f2bf(b2.z); o[7] = f2bf(b2.w);
  *(u16x8*)(dst + i) = o;
}

__global__ __launch_bounds__(256) void cvt_hx_k(const float* __restrict__ hx, u16* __restrict__ hb,
                                                float* __restrict__ hf) {
  size_t i = ((size_t)blockIdx.x * 256 + threadIdx.x) * 8;
  float4 a = *(const float4*)(hx + i);
  float4 b2 = *(const float4*)(hx + i + 4);
  u16x8 o;
  o[0] = f2bf(a.x); o[1] = f2bf(a.y); o[2] = f2bf(a.z); o[3] = f2bf(a.w);
  o[4] = f2bf(b2.x); o[5] = f2bf(b2.y); o[6] = f2bf(b2.z); o[7] = f2bf(b2.w);
  *(u16x8*)(hb + i) = o;
  *(float4*)(hf + i) = a;
  *(float4*)(hf + i + 4) = b2;
}

// gate-interleave permutation: out row n' = j*48+s (s: 0-15 r, 16-31 z, 32-47 n)
__global__ __launch_bounds__(256) void perm_w_k(const float* __restrict__ Wih, const float* __restrict__ Whh,
                                                const float* __restrict__ bih, const float* __restrict__ bhh,
                                                u16* __restrict__ Wihp, u16* __restrict__ Whhp,
                                                float* __restrict__ bihp, float* __restrict__ bhhp) {
  int np = blockIdx.x, tid = threadIdx.x;
  int j = np / 48, s2 = np - j * 48;
  int orig = (s2 >> 4) * kH + j * 16 + (s2 & 15);
  float4 a = ((const float4*)(Wih + (size_t)orig * kD))[tid];
  float4 b2 = ((const float4*)(Whh + (size_t)orig * kH))[tid];
  u16x4 oa, ob;
  oa[0] = f2bf(a.x); oa[1] = f2bf(a.y); oa[2] = f2bf(a.z); oa[3] = f2bf(a.w);
  ob[0] = f2bf(b2.x); ob[1] = f2bf(b2.y); ob[2] = f2bf(b2.z); ob[3] = f2bf(b2.w);
  *(u16x4*)(Wihp + (size_t)np * kD + tid * 4) = oa;
  *(u16x4*)(Whhp + (size_t)np * kH + tid * 4) = ob;
  if (tid == 0) { bihp[np] = bih[orig]; bhhp[np] = bhh[orig]; }
}

// ---------------- gi GEMM: m97-style 128x128 bf16 MFMA (unchanged) ----------------

__global__ __launch_bounds__(256) void gi_gemm_k(const u16* __restrict__ A, const u16* __restrict__ Bw,
                                                 const float* __restrict__ bih, u16* __restrict__ gi) {
  __shared__ u16 As[128 * 32];
  __shared__ u16 Bs[128 * 32];
  int bid = blockIdx.x;
  int b2 = (bid & 7) * 768 + (bid >> 3);
  int m0 = (b2 / 24) * 128, n0 = (b2 % 24) * 128;
  int tid = threadIdx.x, w = tid >> 6, lane = tid & 63;
  int wm = (w >> 1) * 64, wn = (w & 1) * 64;
  f32x4 acc[4][4] = {};
  for (int kt = 0; kt < 32; ++kt) {
    int k0 = kt * 32;
#pragma unroll
    for (int p = 0; p < 2; ++p) {
      int c = w * 2 + p;
      int e = c * 512 + lane * 8;
      int row = e >> 5, kk = e & 31;
      glds16(A + (size_t)(m0 + row) * kD + k0 + kk, (char*)As + c * 1024);
      glds16(Bw + (size_t)(n0 + row) * kD + k0 + kk, (char*)Bs + c * 1024);
    }
    __syncthreads();
    int fr = lane & 15, fo = (lane >> 4) * 16;
    s16x8 af[4], bfr[4];
#pragma unroll
    for (int mi = 0; mi < 4; ++mi)
      af[mi] = *(const s16x8*)((const char*)As + (wm + mi * 16 + fr) * 64 + fo);
#pragma unroll
    for (int ni = 0; ni < 4; ++ni)
      bfr[ni] = *(const s16x8*)((const char*)Bs + (wn + ni * 16 + fr) * 64 + fo);
#pragma unroll
    for (int mi = 0; mi < 4; ++mi)
#pragma unroll
      for (int ni = 0; ni < 4; ++ni)
        acc[mi][ni] = __builtin_amdgcn_mfma_f32_16x16x32_bf16(af[mi], bfr[ni], acc[mi][ni], 0, 0, 0);
    __syncthreads();
  }
  int fr = lane & 15, rb = (lane >> 4) * 4;
#pragma unroll
  for (int ni = 0; ni < 4; ++ni) {
    int n = n0 + wn + ni * 16 + fr;
    float bv = bih[n];
#pragma unroll
    for (int mi = 0; mi < 4; ++mi) {
#pragma unroll
      for (int i2 = 0; i2 < 4; ++i2) {
        int m = m0 + wm + mi * 16 + rb + i2;
        int b = m >> 7, t = m & 127;
        gi[((size_t)t * kB + b) * kG + n] = f2bf(acc[mi][ni][i2] + bv);
      }
    }
  }
}

// ---------------- one recurrence step (v2) ----------------
// grid (64 Ng, 4 Mg), 256 thr, dynamic LDS 147456 B.
// Wc: [8 kc][48 rows][128 u16] chunk-major, XOR-swizzled.
// Hc: 3 x [64 rows][128 u16], XOR-swizzled.
// Per kc: wave stages 3 W + 4 h segments (glds16, inverse-swizzled source),
// 2-deep lookahead, counted vmcnt(7), raw s_barrier. 12 MFMA per kc.

__global__ void gru_step2_k(const u16* __restrict__ Whh, const u16* __restrict__ gi,
                            const float* __restrict__ bhh, const int* __restrict__ is_init,
                            const u16* __restrict__ hb_prev, u16* __restrict__ hb_next,
                            const float* __restrict__ hf_prev, float* __restrict__ hf_next,
                            float* __restrict__ Hs, int t) {
  extern __shared__ char smem[];
  char* Wc = smem;             // 98304 B
  char* Hc = smem + 98304;     // 49152 B
  int Ng = blockIdx.x, Mg = blockIdx.y;
  int tid = threadIdx.x, w = tid >> 6, lane = tid & 63;
  int fr = lane & 15, q = lane >> 4;
  int fo = q * 16;
  int sw = (fr & 7) << 4;
  const u16* Wbase = Whh + (size_t)(48 * Ng) * kH;
  const u16* Hbase = hb_prev + (size_t)(Mg * 64) * kH;

  auto stage = [&](int kc) {
#pragma unroll
    for (int i = 0; i < 3; ++i) {        // W chunk kc: 48x128 u16 = 12 KB
      int c = w * 3 + i;
      int d = c * 512 + lane * 8;        // u16 idx in chunk, < 6144
      int row = d >> 7;
      int col = (d & 127) ^ ((row & 7) << 3);
      glds16(Wbase + (size_t)row * kH + kc * 128 + col, Wc + kc * 12288 + c * 1024);
    }
#pragma unroll
    for (int i = 0; i < 4; ++i) {        // h chunk kc: 64x128 u16 = 16 KB
      int c = w * 4 + i;
      int d = c * 512 + lane * 8;        // < 8192
      int row = d >> 7;
      int col = (d & 127) ^ ((row & 7) << 3);
      glds16(Hbase + (size_t)row * kH + kc * 128 + col, Hc + (kc % 3) * 16384 + c * 1024);
    }
  };

  f32x4 acc[3] = {};
  stage(0); stage(1);
  asm volatile("s_waitcnt vmcnt(7)" ::: "memory");   // chunk 0 landed
  __builtin_amdgcn_s_barrier();
  int hrow = w * 16 + fr;
#pragma unroll
  for (int kc = 0; kc < 8; ++kc) {
    if (kc + 2 < 8) stage(kc + 2);
    const char* hbuf = Hc + (kc % 3) * 16384;
    const char* wbuf = Wc + kc * 12288;
#pragma unroll
    for (int ks = 0; ks < 4; ++ks) {
      s16x8 hf8 = *(const s16x8*)(hbuf + ((hrow * 256 + ks * 64 + fo) ^ sw));
#pragma unroll
      for (int g = 0; g < 3; ++g) {
        int wrow = g * 16 + fr;
        const s16x8* wp = (const s16x8*)(wbuf + ((wrow * 256 + ks * 64 + fo) ^ sw));
        acc[g] = __builtin_amdgcn_mfma_f32_16x16x32_bf16(hf8, *wp, acc[g], 0, 0, 0);
      }
    }
    if (kc < 7) {
      if (kc < 6) asm volatile("s_waitcnt vmcnt(7)" ::: "memory");  // chunk kc+1 landed
      else        asm volatile("s_waitcnt vmcnt(0)" ::: "memory");
      __builtin_amdgcn_s_barrier();
    }
  }
  // ---- epilogue: gates + h update (identical math to validated round-2) ----
  int hcol = Ng * 16 + fr;
  float br = bhh[48 * Ng + fr], bz = bhh[48 * Ng + 16 + fr], bn = bhh[48 * Ng + 32 + fr];
#pragma unroll
  for (int i = 0; i < 4; ++i) {
    int b = Mg * 64 + w * 16 + q * 4 + i;
    float m = is_init[b * kT + t] ? 0.f : 1.f;
    size_t gb = ((size_t)t * kB + b) * (size_t)kG + 48 * Ng;
    float gir = bf2f(gi[gb + fr]);
    float giz = bf2f(gi[gb + 16 + fr]);
    float gin = bf2f(gi[gb + 32 + fr]);
    float r = sigm(gir + m * acc[0][i] + br);
    float z = sigm(giz + m * acc[1][i] + bz);
    float n = ftanh(gin + r * (m * acc[2][i] + bn));
    float hp = m * hf_prev[(size_t)b * kH + hcol];
    float hv = (1.f - z) * n + z * hp;
    hb_next[(size_t)b * kH + hcol] = f2bf(hv);
    hf_next[(size_t)b * kH + hcol] = hv;
    Hs[((size_t)b * kT + t) * kH + hcol] = hv;
  }
}

// ---------------- LayerNorm + gated residual ----------------

__global__ __launch_bounds__(256) void ln_res_k(const float* __restrict__ Hs, const float* __restrict__ x,
                                                const float* __restrict__ g, const float* __restrict__ be,
                                                const float* __restrict__ rg, float* __restrict__ Y) {
  int row = blockIdx.x;
  int tid = threadIdx.x;
  size_t base = (size_t)row * kH;
  float4 v = ((const float4*)(Hs + base))[tid];
  float s = v.x + v.y + v.z + v.w;
  float ss = v.x * v.x + v.y * v.y + v.z * v.z + v.w * v.w;
#pragma unroll
  for (int off = 32; off > 0; off >>= 1) {
    s += __shfl_down(s, off);
    ss += __shfl_down(ss, off);
  }
  __shared__ float red[8];
  int w = tid >> 6;
  if ((tid & 63) == 0) { red[w] = s; red[4 + w] = ss; }
  __syncthreads();
  s = red[0] + red[1] + red[2] + red[3];
  ss = red[4] + red[5] + red[6] + red[7];
  float mu = s * (1.f / kH);
  float rs = rsqrtf(ss * (1.f / kH) - mu * mu + 1e-5f);
  float4 xv = ((const float4*)(x + base))[tid];
  float4 gv = ((const float4*)g)[tid];
  float4 bv = ((const float4*)be)[tid];
  float4 rv = ((const float4*)rg)[tid];
  float4 o;
  o.x = (v.x - mu) * rs * gv.x + bv.x + xv.x * sigm(rv.x);
  o.y = (v.y - mu) * rs * gv.y + bv.y + xv.y * sigm(rv.y);
  o.z = (v.z - mu) * rs * gv.z + bv.z + xv.z * sigm(rv.z);
  o.w = (v.w - mu) * rs * gv.w + bv.w + xv.w * sigm(rv.w);
  ((float4*)(Y + base))[tid] = o;
}

// ---------------- launch ----------------

extern "C" void kernel_launch(void* const* d_in, const int* in_sizes, int n_in,
                              void* d_out, int out_size, void* d_ws, size_t ws_size,
                              hipStream_t stream) {
  const float* x = (const float*)d_in[0];
  const float* hx = (const float*)d_in[1];
  const int* is_init = (const int*)d_in[2];
  const float* Wih = (const float*)d_in[3];
  const float* Whh = (const float*)d_in[4];
  const float* bih = (const float*)d_in[5];
  const float* bhh = (const float*)d_in[6];
  const float* lng = (const float*)d_in[7];
  const float* lnb = (const float*)d_in[8];
  const float* rg = (const float*)d_in[9];
  float* Y = (float*)d_out;
  float* Hs = Y + (size_t)kB * kT * kH;

  char* ws = (char*)d_ws;
  u16* xb = (u16*)(ws + 0);                 //  67,108,864 B
  u16* Wihp = (u16*)(ws + 67108864);        //   6,291,456
  u16* Whhp = (u16*)(ws + 73400320);        //   6,291,456
  float* bihp = (float*)(ws + 79691776);    //      12,288
  float* bhhp = (float*)(ws + 79704064);    //      12,288
  u16* hb0 = (u16*)(ws + 79716352);         //     524,288
  u16* hb1 = (u16*)(ws + 80240640);         //     524,288
  float* hf0 = (float*)(ws + 80764928);     //   1,048,576
  float* hf1 = (float*)(ws + 81813504);     //   1,048,576
  u16* gi = (u16*)(ws + 82862080);          // 201,326,592 -> total 284,188,672
  if (ws_size < 284188672ull) return;

  cvt_bf16_k<<<16384, 256, 0, stream>>>(x, xb);
  perm_w_k<<<3072, 256, 0, stream>>>(Wih, Whh, bih, bhh, Wihp, Whhp, bihp, bhhp);
  cvt_hx_k<<<128, 256, 0, stream>>>(hx, hb0, hf0);
  gi_gemm_k<<<6144, 256, 0, stream>>>(xb, Wihp, bihp, gi);

  (void)hipFuncSetAttribute((const void*)gru_step2_k,
                            hipFuncAttributeMaxDynamicSharedMemorySize, 147456);
  for (int t = 0; t < kT; ++t) {
    const u16* hbp = (t & 1) ? hb1 : hb0;
    u16* hbn = (t & 1) ? hb0 : hb1;
    const float* hfp = (t & 1) ? hf1 : hf0;
    float* hfn = (t & 1) ? hf0 : hf1;
    gru_step2_k<<<dim3(64, 4), 256, 147456, stream>>>(Whhp, gi, bhhp, is_init,
                                                      hbp, hbn, hfp, hfn, Hs, t);
  }
  ln_res_k<<<32768, 256, 0, stream>>>(Hs, x, lng, lnb, rg, Y);
}

// Round 6
// 1705.528 us; speedup vs baseline: 3.2753x; 1.0610x over previous
//
#include <hip/hip_runtime.h>
#include <cstdint>
#include <cstddef>

// GRUCore B=256 T=128 D=1024 H=1024 — Round 6: step kernel de-latencied.
// vs round 5: (1) epilogue operands (gi/is_init/hf_prev/bhh) prefetched at
// kernel entry (issued before first counted vmcnt -> counts stay safe);
// (2) 3-deep chunk lookahead, 4-slot W/H LDS buffers (112 KB);
// (3) s_setprio around MFMA clusters. gi GEMM / prep / LN unchanged.

constexpr int kB = 256, kT = 128, kD = 1024, kH = 1024, kG = 3072;

typedef unsigned short u16;
typedef unsigned int u32;
typedef __attribute__((ext_vector_type(4))) float f32x4;
typedef __attribute__((ext_vector_type(8))) short s16x8;
typedef __attribute__((ext_vector_type(8))) u16 u16x8;
typedef __attribute__((ext_vector_type(4))) u16 u16x4;

__device__ __forceinline__ u16 f2bf(float f) {
  u32 u = __builtin_bit_cast(u32, f);
  u += 0x7fffu + ((u >> 16) & 1u);
  return (u16)(u >> 16);
}
__device__ __forceinline__ float bf2f(u16 s) {
  return __builtin_bit_cast(float, (u32)s << 16);
}
__device__ __forceinline__ void glds16(const void* g, void* l) {
  __builtin_amdgcn_global_load_lds(
      (const __attribute__((address_space(1))) u32*)g,
      (__attribute__((address_space(3))) u32*)l, 16, 0, 0);
}
__device__ __forceinline__ float sigm(float x) { return 1.f / (1.f + __expf(-x)); }
__device__ __forceinline__ float ftanh(float x) {
  float e = __expf(2.f * x);
  return 1.f - 2.f / (e + 1.f);
}

// ---------------- prep kernels ----------------

__global__ __launch_bounds__(256) void cvt_bf16_k(const float* __restrict__ src, u16* __restrict__ dst) {
  size_t i = ((size_t)blockIdx.x * 256 + threadIdx.x) * 8;
  float4 a = *(const float4*)(src + i);
  float4 b2 = *(const float4*)(src + i + 4);
  u16x8 o;
  o[0] = f2bf(a.x); o[1] = f2bf(a.y); o[2] = f2bf(a.z); o[3] = f2bf(a.w);
  o[4] = f2bf(b2.x); o[5] = f2bf(b2.y); o[6] = f2bf(b2.z); o[7] = f2bf(b2.w);
  *(u16x8*)(dst + i) = o;
}

__global__ __launch_bounds__(256) void cvt_hx_k(const float* __restrict__ hx, u16* __restrict__ hb,
                                                float* __restrict__ hf) {
  size_t i = ((size_t)blockIdx.x * 256 + threadIdx.x) * 8;
  float4 a = *(const float4*)(hx + i);
  float4 b2 = *(const float4*)(hx + i + 4);
  u16x8 o;
  o[0] = f2bf(a.x); o[1] = f2bf(a.y); o[2] = f2bf(a.z); o[3] = f2bf(a.w);
  o[4] = f2bf(b2.x); o[5] = f2bf(b2.y); o[6] = f2bf(b2.z); o[7] = f2bf(b2.w);
  *(u16x8*)(hb + i) = o;
  *(float4*)(hf + i) = a;
  *(float4*)(hf + i + 4) = b2;
}

// gate-interleave permutation: out row n' = j*48+s (s: 0-15 r, 16-31 z, 32-47 n)
__global__ __launch_bounds__(256) void perm_w_k(const float* __restrict__ Wih, const float* __restrict__ Whh,
                                                const float* __restrict__ bih, const float* __restrict__ bhh,
                                                u16* __restrict__ Wihp, u16* __restrict__ Whhp,
                                                float* __restrict__ bihp, float* __restrict__ bhhp) {
  int np = blockIdx.x, tid = threadIdx.x;
  int j = np / 48, s2 = np - j * 48;
  int orig = (s2 >> 4) * kH + j * 16 + (s2 & 15);
  float4 a = ((const float4*)(Wih + (size_t)orig * kD))[tid];
  float4 b2 = ((const float4*)(Whh + (size_t)orig * kH))[tid];
  u16x4 oa, ob;
  oa[0] = f2bf(a.x); oa[1] = f2bf(a.y); oa[2] = f2bf(a.z); oa[3] = f2bf(a.w);
  ob[0] = f2bf(b2.x); ob[1] = f2bf(b2.y); ob[2] = f2bf(b2.z); ob[3] = f2bf(b2.w);
  *(u16x4*)(Wihp + (size_t)np * kD + tid * 4) = oa;
  *(u16x4*)(Whhp + (size_t)np * kH + tid * 4) = ob;
  if (tid == 0) { bihp[np] = bih[orig]; bhhp[np] = bhh[orig]; }
}

// ---------------- gi GEMM: m97-style 128x128 bf16 MFMA (unchanged) ----------------

__global__ __launch_bounds__(256) void gi_gemm_k(const u16* __restrict__ A, const u16* __restrict__ Bw,
                                                 const float* __restrict__ bih, u16* __restrict__ gi) {
  __shared__ u16 As[128 * 32];
  __shared__ u16 Bs[128 * 32];
  int bid = blockIdx.x;
  int b2 = (bid & 7) * 768 + (bid >> 3);
  int m0 = (b2 / 24) * 128, n0 = (b2 % 24) * 128;
  int tid = threadIdx.x, w = tid >> 6, lane = tid & 63;
  int wm = (w >> 1) * 64, wn = (w & 1) * 64;
  f32x4 acc[4][4] = {};
  for (int kt = 0; kt < 32; ++kt) {
    int k0 = kt * 32;
#pragma unroll
    for (int p = 0; p < 2; ++p) {
      int c = w * 2 + p;
      int e = c * 512 + lane * 8;
      int row = e >> 5, kk = e & 31;
      glds16(A + (size_t)(m0 + row) * kD + k0 + kk, (char*)As + c * 1024);
      glds16(Bw + (size_t)(n0 + row) * kD + k0 + kk, (char*)Bs + c * 1024);
    }
    __syncthreads();
    int fr = lane & 15, fo = (lane >> 4) * 16;
    s16x8 af[4], bfr[4];
#pragma unroll
    for (int mi = 0; mi < 4; ++mi)
      af[mi] = *(const s16x8*)((const char*)As + (wm + mi * 16 + fr) * 64 + fo);
#pragma unroll
    for (int ni = 0; ni < 4; ++ni)
      bfr[ni] = *(const s16x8*)((const char*)Bs + (wn + ni * 16 + fr) * 64 + fo);
#pragma unroll
    for (int mi = 0; mi < 4; ++mi)
#pragma unroll
      for (int ni = 0; ni < 4; ++ni)
        acc[mi][ni] = __builtin_amdgcn_mfma_f32_16x16x32_bf16(af[mi], bfr[ni], acc[mi][ni], 0, 0, 0);
    __syncthreads();
  }
  int fr = lane & 15, rb = (lane >> 4) * 4;
#pragma unroll
  for (int ni = 0; ni < 4; ++ni) {
    int n = n0 + wn + ni * 16 + fr;
    float bv = bih[n];
#pragma unroll
    for (int mi = 0; mi < 4; ++mi) {
#pragma unroll
      for (int i2 = 0; i2 < 4; ++i2) {
        int m = m0 + wm + mi * 16 + rb + i2;
        int b = m >> 7, t = m & 127;
        gi[((size_t)t * kB + b) * kG + n] = f2bf(acc[mi][ni][i2] + bv);
      }
    }
  }
}

// ---------------- one recurrence step (v3) ----------------
// grid (64 Ng, 4 Mg), 256 thr, dynamic LDS 114688 B.
// Wc: 4 slots x [48][128] u16 (12 KB), Hc: 4 slots x [64][128] u16 (16 KB),
// both XOR-swizzled. 3-deep chunk lookahead, counted vmcnt(14/7/0).
// Epilogue operands prefetched at entry (before first counted wait).

__global__ void gru_step3_k(const u16* __restrict__ Whh, const u16* __restrict__ gi,
                            const float* __restrict__ bhh, const int* __restrict__ is_init,
                            const u16* __restrict__ hb_prev, u16* __restrict__ hb_next,
                            const float* __restrict__ hf_prev, float* __restrict__ hf_next,
                            float* __restrict__ Hs, int t) {
  extern __shared__ char smem[];
  char* Wc = smem;             // 4 * 12288 = 49152 B
  char* Hc = smem + 49152;     // 4 * 16384 = 65536 B
  int Ng = blockIdx.x, Mg = blockIdx.y;
  int tid = threadIdx.x, w = tid >> 6, lane = tid & 63;
  int fr = lane & 15, q = lane >> 4;
  int fo = q * 16;
  int sw = (fr & 7) << 4;
  const u16* Wbase = Whh + (size_t)(48 * Ng) * kH;
  const u16* Hbase = hb_prev + (size_t)(Mg * 64) * kH;

  // ---- epilogue prefetch (no dependence on h; issued before any counted wait) ----
  int hcol = Ng * 16 + fr;
  float br = bhh[48 * Ng + fr], bz = bhh[48 * Ng + 16 + fr], bn = bhh[48 * Ng + 32 + fr];
  float gir[4], giz[4], gin[4], hpf[4], msk[4];
#pragma unroll
  for (int i = 0; i < 4; ++i) {
    int b = Mg * 64 + w * 16 + q * 4 + i;
    msk[i] = is_init[b * kT + t] ? 0.f : 1.f;
    size_t gb = ((size_t)t * kB + b) * (size_t)kG + 48 * Ng;
    gir[i] = bf2f(gi[gb + fr]);
    giz[i] = bf2f(gi[gb + 16 + fr]);
    gin[i] = bf2f(gi[gb + 32 + fr]);
    hpf[i] = hf_prev[(size_t)b * kH + hcol];
  }

  auto stage = [&](int kc) {
#pragma unroll
    for (int i = 0; i < 3; ++i) {        // W chunk kc: 48x128 u16 = 12 KB
      int c = w * 3 + i;
      int d = c * 512 + lane * 8;
      int row = d >> 7;
      int col = (d & 127) ^ ((row & 7) << 3);
      glds16(Wbase + (size_t)row * kH + kc * 128 + col, Wc + (kc & 3) * 12288 + c * 1024);
    }
#pragma unroll
    for (int i = 0; i < 4; ++i) {        // h chunk kc: 64x128 u16 = 16 KB
      int c = w * 4 + i;
      int d = c * 512 + lane * 8;
      int row = d >> 7;
      int col = (d & 127) ^ ((row & 7) << 3);
      glds16(Hbase + (size_t)row * kH + kc * 128 + col, Hc + (kc & 3) * 16384 + c * 1024);
    }
  };

  f32x4 acc[3] = {};
  stage(0); stage(1); stage(2);
  asm volatile("s_waitcnt vmcnt(14)" ::: "memory");   // chunk 0 landed
  __builtin_amdgcn_s_barrier();
  int hrow = w * 16 + fr;
#pragma unroll
  for (int kc = 0; kc < 8; ++kc) {
    if (kc + 3 < 8) stage(kc + 3);
    const char* hbuf = Hc + (kc & 3) * 16384;
    const char* wbuf = Wc + (kc & 3) * 12288;
    __builtin_amdgcn_s_setprio(1);
#pragma unroll
    for (int ks = 0; ks < 4; ++ks) {
      s16x8 hf8 = *(const s16x8*)(hbuf + ((hrow * 256 + ks * 64 + fo) ^ sw));
#pragma unroll
      for (int g = 0; g < 3; ++g) {
        int wrow = g * 16 + fr;
        const s16x8* wp = (const s16x8*)(wbuf + ((wrow * 256 + ks * 64 + fo) ^ sw));
        acc[g] = __builtin_amdgcn_mfma_f32_16x16x32_bf16(hf8, *wp, acc[g], 0, 0, 0);
      }
    }
    __builtin_amdgcn_s_setprio(0);
    if (kc < 7) {
      if (kc < 5)       asm volatile("s_waitcnt vmcnt(14)" ::: "memory");  // chunk kc+1 landed
      else if (kc == 5) asm volatile("s_waitcnt vmcnt(7)" ::: "memory");
      else              asm volatile("s_waitcnt vmcnt(0)" ::: "memory");
      __builtin_amdgcn_s_barrier();
    }
  }
  // ---- epilogue: gates + h update (operands already in registers) ----
#pragma unroll
  for (int i = 0; i < 4; ++i) {
    int b = Mg * 64 + w * 16 + q * 4 + i;
    float m = msk[i];
    float r = sigm(gir[i] + m * acc[0][i] + br);
    float z = sigm(giz[i] + m * acc[1][i] + bz);
    float n = ftanh(gin[i] + r * (m * acc[2][i] + bn));
    float hv = (1.f - z) * n + z * (m * hpf[i]);
    hb_next[(size_t)b * kH + hcol] = f2bf(hv);
    hf_next[(size_t)b * kH + hcol] = hv;
    Hs[((size_t)b * kT + t) * kH + hcol] = hv;
  }
}

// ---------------- LayerNorm + gated residual ----------------

__global__ __launch_bounds__(256) void ln_res_k(const float* __restrict__ Hs, const float* __restrict__ x,
                                                const float* __restrict__ g, const float* __restrict__ be,
                                                const float* __restrict__ rg, float* __restrict__ Y) {
  int row = blockIdx.x;
  int tid = threadIdx.x;
  size_t base = (size_t)row * kH;
  float4 v = ((const float4*)(Hs + base))[tid];
  float s = v.x + v.y + v.z + v.w;
  float ss = v.x * v.x + v.y * v.y + v.z * v.z + v.w * v.w;
#pragma unroll
  for (int off = 32; off > 0; off >>= 1) {
    s += __shfl_down(s, off);
    ss += __shfl_down(ss, off);
  }
  __shared__ float red[8];
  int w = tid >> 6;
  if ((tid & 63) == 0) { red[w] = s; red[4 + w] = ss; }
  __syncthreads();
  s = red[0] + red[1] + red[2] + red[3];
  ss = red[4] + red[5] + red[6] + red[7];
  float mu = s * (1.f / kH);
  float rs = rsqrtf(ss * (1.f / kH) - mu * mu + 1e-5f);
  float4 xv = ((const float4*)(x + base))[tid];
  float4 gv = ((const float4*)g)[tid];
  float4 bv = ((const float4*)be)[tid];
  float4 rv = ((const float4*)rg)[tid];
  float4 o;
  o.x = (v.x - mu) * rs * gv.x + bv.x + xv.x * sigm(rv.x);
  o.y = (v.y - mu) * rs * gv.y + bv.y + xv.y * sigm(rv.y);
  o.z = (v.z - mu) * rs * gv.z + bv.z + xv.z * sigm(rv.z);
  o.w = (v.w - mu) * rs * gv.w + bv.w + xv.w * sigm(rv.w);
  ((float4*)(Y + base))[tid] = o;
}

// ---------------- launch ----------------

extern "C" void kernel_launch(void* const* d_in, const int* in_sizes, int n_in,
                              void* d_out, int out_size, void* d_ws, size_t ws_size,
                              hipStream_t stream) {
  const float* x = (const float*)d_in[0];
  const float* hx = (const float*)d_in[1];
  const int* is_init = (const int*)d_in[2];
  const float* Wih = (const float*)d_in[3];
  const float* Whh = (const float*)d_in[4];
  const float* bih = (const float*)d_in[5];
  const float* bhh = (const float*)d_in[6];
  const float* lng = (const float*)d_in[7];
  const float* lnb = (const float*)d_in[8];
  const float* rg = (const float*)d_in[9];
  float* Y = (float*)d_out;
  float* Hs = Y + (size_t)kB * kT * kH;

  char* ws = (char*)d_ws;
  u16* xb = (u16*)(ws + 0);                 //  67,108,864 B
  u16* Wihp = (u16*)(ws + 67108864);        //   6,291,456
  u16* Whhp = (u16*)(ws + 73400320);        //   6,291,456
  float* bihp = (float*)(ws + 79691776);    //      12,288
  float* bhhp = (float*)(ws + 79704064);    //      12,288
  u16* hb0 = (u16*)(ws + 79716352);         //     524,288
  u16* hb1 = (u16*)(ws + 80240640);         //     524,288
  float* hf0 = (float*)(ws + 80764928);     //   1,048,576
  float* hf1 = (float*)(ws + 81813504);     //   1,048,576
  u16* gi = (u16*)(ws + 82862080);          // 201,326,592 -> total 284,188,672
  if (ws_size < 284188672ull) return;

  cvt_bf16_k<<<16384, 256, 0, stream>>>(x, xb);
  perm_w_k<<<3072, 256, 0, stream>>>(Wih, Whh, bih, bhh, Wihp, Whhp, bihp, bhhp);
  cvt_hx_k<<<128, 256, 0, stream>>>(hx, hb0, hf0);
  gi_gemm_k<<<6144, 256, 0, stream>>>(xb, Wihp, bihp, gi);

  (void)hipFuncSetAttribute((const void*)gru_step3_k,
                            hipFuncAttributeMaxDynamicSharedMemorySize, 114688);
  for (int t = 0; t < kT; ++t) {
    const u16* hbp = (t & 1) ? hb1 : hb0;
    u16* hbn = (t & 1) ? hb0 : hb1;
    const float* hfp = (t & 1) ? hf1 : hf0;
    float* hfn = (t & 1) ? hf0 : hf1;
    gru_step3_k<<<dim3(64, 4), 256, 114688, stream>>>(Whhp, gi, bhhp, is_init,
                                                      hbp, hbn, hfp, hfn, Hs, t);
  }
  ln_res_k<<<32768, 256, 0, stream>>>(Hs, x, lng, lnb, rg, Y);
}